// Round 2
// baseline (1021.315 us; speedup 1.0000x reference)
//
#include <hip/hip_runtime.h>
#include <math.h>

// IPA: N=768, H=12, SQK=SV=16, PQK=4, PV=8, C1=384, C2=128, COUT=384, DCAT=2112
#define LROW 772   // padded LDS logits row (bank-spread for per-head float4 reads)

__device__ __forceinline__ float softplusf(float x) {
  return fmaxf(x, 0.f) + log1pf(expf(-fabsf(x)));
}

// ---------------- kernel 1: fused input projections -> proj (768 x 1152) ----
// cols: [0,192) q_scalar | [192,576) kv_scalar (h*32+s, s<16 k, s>=16 v)
//       [576,720) qp (j*48+h*4+p) | [720,1152) kvp (j*144+h*12+pidx)
__global__ __launch_bounds__(256) void k_proj(
    const float* __restrict__ x,
    const float* __restrict__ qs_w,  const float* __restrict__ qs_b,
    const float* __restrict__ kvs_w, const float* __restrict__ kvs_b,
    const float* __restrict__ qp_w,  const float* __restrict__ qp_b,
    const float* __restrict__ kvp_w, const float* __restrict__ kvp_b,
    float* __restrict__ proj)
{
  const int t = threadIdx.x;
  const int col = blockIdx.x * 64 + (t & 63);
  const int g = __builtin_amdgcn_readfirstlane(t >> 6);
  const int n0 = blockIdx.y * 16 + g * 4;

  const float* W; const float* Bp; int ld, cc;
  if (col < 192)      { W = qs_w;  Bp = qs_b;  ld = 192; cc = col; }
  else if (col < 576) { W = kvs_w; Bp = kvs_b; ld = 384; cc = col - 192; }
  else if (col < 720) { W = qp_w;  Bp = qp_b;  ld = 144; cc = col - 576; }
  else                { W = kvp_w; Bp = kvp_b; ld = 432; cc = col - 720; }

  const float b = Bp[cc];
  float acc0 = b, acc1 = b, acc2 = b, acc3 = b;
  const float* xr = x + (size_t)n0 * 384;   // wave-uniform -> s_load
  #pragma unroll 4
  for (int k = 0; k < 384; ++k) {
    const float w = W[(size_t)k * ld + cc];
    acc0 = fmaf(xr[k],        w, acc0);
    acc1 = fmaf(xr[384 + k],  w, acc1);
    acc2 = fmaf(xr[768 + k],  w, acc2);
    acc3 = fmaf(xr[1152 + k], w, acc3);
  }
  proj[(size_t)(n0+0)*1152 + col] = acc0;
  proj[(size_t)(n0+1)*1152 + col] = acc1;
  proj[(size_t)(n0+2)*1152 + col] = acc2;
  proj[(size_t)(n0+3)*1152 + col] = acc3;
}

// ---------------- kernel 2: point transforms + transposed V layouts ---------
// qpt/kpt: [n][h*4+pq][4] (i padded to 4); vsT: [(h*16+d)][m]; vpT: [((h*8+p)*3+i)][m]
__global__ __launch_bounds__(192) void k_points(
    const float* __restrict__ proj,
    const float* __restrict__ rot, const float* __restrict__ trans,
    float* __restrict__ qpt, float* __restrict__ kpt,
    float* __restrict__ vsT, float* __restrict__ vpT)
{
  const int n = blockIdx.x;
  const int t = threadIdx.x;
  const float* pr = proj + (size_t)n * 1152;
  const float* R = rot + n * 9;
  const float* T = trans + n * 3;

  { // v_scalar transpose
    const int h = t >> 4, d = t & 15;
    vsT[(size_t)t * 768 + n] = pr[192 + h * 32 + 16 + d];
  }
  if (t < 48) { // q points: col = 576 + j*48 + t
    const float l0 = pr[576 + t];
    const float l1 = pr[576 + 48 + t];
    const float l2 = pr[576 + 96 + t];
    const int b = n * 192 + t * 4;
    qpt[b+0] = R[0]*l0 + R[1]*l1 + R[2]*l2 + T[0];
    qpt[b+1] = R[3]*l0 + R[4]*l1 + R[5]*l2 + T[1];
    qpt[b+2] = R[6]*l0 + R[7]*l1 + R[8]*l2 + T[2];
    qpt[b+3] = 0.f;
  } else { // kv points: idx = h*12+pidx; col = 720 + j*144 + idx
    const int idx = t - 48;
    const float l0 = pr[720 + idx];
    const float l1 = pr[720 + 144 + idx];
    const float l2 = pr[720 + 288 + idx];
    const float g0 = R[0]*l0 + R[1]*l1 + R[2]*l2 + T[0];
    const float g1 = R[3]*l0 + R[4]*l1 + R[5]*l2 + T[1];
    const float g2 = R[6]*l0 + R[7]*l1 + R[8]*l2 + T[2];
    const int h = idx / 12, pidx = idx % 12;
    if (pidx < 8) { // v_point
      const int row = (h * 8 + pidx) * 3;
      vpT[(size_t)(row+0)*768 + n] = g0;
      vpT[(size_t)(row+1)*768 + n] = g1;
      vpT[(size_t)(row+2)*768 + n] = g2;
    } else {        // k_point
      const int b = n * 192 + (h * 4 + (pidx - 8)) * 4;
      kpt[b+0] = g0; kpt[b+1] = g1; kpt[b+2] = g2; kpt[b+3] = 0.f;
    }
  }
}

// ---------------- kernel 3: per-n fused attention ---------------------------
#define ACC12(vv, c) { \
  const float4 w0 = a2w4[(c)*3+0]; \
  const float4 w1 = a2w4[(c)*3+1]; \
  const float4 w2 = a2w4[(c)*3+2]; \
  bb[0]=fmaf(vv,w0.x,bb[0]); bb[1]=fmaf(vv,w0.y,bb[1]); bb[2]=fmaf(vv,w0.z,bb[2]); bb[3]=fmaf(vv,w0.w,bb[3]); \
  bb[4]=fmaf(vv,w1.x,bb[4]); bb[5]=fmaf(vv,w1.y,bb[5]); bb[6]=fmaf(vv,w1.z,bb[6]); bb[7]=fmaf(vv,w1.w,bb[7]); \
  bb[8]=fmaf(vv,w2.x,bb[8]); bb[9]=fmaf(vv,w2.y,bb[9]); bb[10]=fmaf(vv,w2.z,bb[10]); bb[11]=fmaf(vv,w2.w,bb[11]); }

__global__ __launch_bounds__(256) void k_attn(
    const float* __restrict__ proj,
    const float* __restrict__ in2d,
    const float* __restrict__ maskp,
    const float* __restrict__ rot, const float* __restrict__ trans,
    const float* __restrict__ tpw,
    const float* __restrict__ a2w, const float* __restrict__ a2b,
    const float* __restrict__ qpt, const float* __restrict__ kpt,
    const float* __restrict__ vsT, const float* __restrict__ vpT,
    float* __restrict__ fact)
{
  __shared__ float l_logits[12 * LROW];
  __shared__ float l_qs[192];
  __shared__ float l_qpt[192];
  __shared__ float l_pw[12];
  __shared__ float l_ptg[288];
  __shared__ float l_maskn;

  const int n = blockIdx.x;
  const int t = threadIdx.x;
  const float SW  = 2.309401076758503f;   // sqrt(16/3)
  const float A2W = 0.5773502691896258f;  // sqrt(1/3)
  const float PWc = 2.449489742783178f;   // sqrt(6)

  // phase 0: stage per-n query-side data
  if (t < 192) l_qs[t] = proj[(size_t)n * 1152 + t];
  if (t < 48)  ((float4*)l_qpt)[t] = ((const float4*)qpt)[n * 48 + t];
  if (t < 12)  l_pw[t] = PWc * softplusf(tpw[t]);
  if (t == 255) l_maskn = maskp[n];

  // phase 1a: bias_2d = A2W*(in2d[n] @ a2_w + a2_b) -> l_logits (thread per m-row)
  const float4* a2w4 = (const float4*)a2w;
  #pragma unroll
  for (int r = 0; r < 3; ++r) {
    const int m = r * 256 + t;
    const float4* row4 = (const float4*)(in2d + ((size_t)n * 768 + m) * 128);
    float bb[12];
    #pragma unroll
    for (int h = 0; h < 12; ++h) bb[h] = 0.f;
    #pragma unroll 4
    for (int c4 = 0; c4 < 32; ++c4) {
      const float4 v = row4[c4];
      ACC12(v.x, c4*4+0)
      ACC12(v.y, c4*4+1)
      ACC12(v.z, c4*4+2)
      ACC12(v.w, c4*4+3)
    }
    #pragma unroll
    for (int h = 0; h < 12; ++h)
      l_logits[h * LROW + m] = A2W * (bb[h] + a2b[h]);
  }
  __syncthreads();

  // phase 1b: add SW*qk_scalar - 0.5*pw*dist2 - mask term
  float mk[3];
  #pragma unroll
  for (int r = 0; r < 3; ++r)
    mk[r] = 100000.f * (1.f - l_maskn * maskp[r*256 + t]);

  for (int h = 0; h < 12; ++h) {
    const float4 qs0 = ((const float4*)l_qs)[h*4+0];
    const float4 qs1 = ((const float4*)l_qs)[h*4+1];
    const float4 qs2 = ((const float4*)l_qs)[h*4+2];
    const float4 qs3 = ((const float4*)l_qs)[h*4+3];
    const float4 qp0 = ((const float4*)l_qpt)[h*4+0];
    const float4 qp1 = ((const float4*)l_qpt)[h*4+1];
    const float4 qp2 = ((const float4*)l_qpt)[h*4+2];
    const float4 qp3 = ((const float4*)l_qpt)[h*4+3];
    const float pwh = l_pw[h];
    #pragma unroll
    for (int r = 0; r < 3; ++r) {
      const int m = r * 256 + t;
      const float4* k4 = (const float4*)(proj + (size_t)m * 1152 + 192 + h * 32);
      float4 kv = k4[0];
      float dot = qs0.x*kv.x + qs0.y*kv.y + qs0.z*kv.z + qs0.w*kv.w;
      kv = k4[1]; dot += qs1.x*kv.x + qs1.y*kv.y + qs1.z*kv.z + qs1.w*kv.w;
      kv = k4[2]; dot += qs2.x*kv.x + qs2.y*kv.y + qs2.z*kv.z + qs2.w*kv.w;
      kv = k4[3]; dot += qs3.x*kv.x + qs3.y*kv.y + qs3.z*kv.z + qs3.w*kv.w;
      const float4* kp4 = (const float4*)(kpt + (size_t)m * 192 + h * 16);
      float4 kp = kp4[0];
      float dx = qp0.x-kp.x, dy = qp0.y-kp.y, dz = qp0.z-kp.z;
      float d2 = dx*dx + dy*dy + dz*dz;
      kp = kp4[1]; dx = qp1.x-kp.x; dy = qp1.y-kp.y; dz = qp1.z-kp.z; d2 += dx*dx + dy*dy + dz*dz;
      kp = kp4[2]; dx = qp2.x-kp.x; dy = qp2.y-kp.y; dz = qp2.z-kp.z; d2 += dx*dx + dy*dy + dz*dz;
      kp = kp4[3]; dx = qp3.x-kp.x; dy = qp3.y-kp.y; dz = qp3.z-kp.z; d2 += dx*dx + dy*dy + dz*dz;
      const int li = h * LROW + m;
      l_logits[li] = l_logits[li] + SW * dot - 0.5f * pwh * d2 - mk[r];
    }
  }
  __syncthreads();

  // phase 2: softmax over m (wave per head, shfl_xor reduce)
  {
    const int w = t >> 6, lane = t & 63;
    #pragma unroll
    for (int hh = 0; hh < 3; ++hh) {
      const int h = w + hh * 4;
      float v[12]; float mx = -3.4e38f;
      #pragma unroll
      for (int i = 0; i < 12; ++i) { v[i] = l_logits[h*LROW + i*64 + lane]; mx = fmaxf(mx, v[i]); }
      #pragma unroll
      for (int off = 32; off; off >>= 1) mx = fmaxf(mx, __shfl_xor(mx, off));
      float s = 0.f;
      #pragma unroll
      for (int i = 0; i < 12; ++i) { v[i] = expf(v[i] - mx); s += v[i]; }
      #pragma unroll
      for (int off = 32; off; off >>= 1) s += __shfl_xor(s, off);
      const float inv = 1.f / s;
      #pragma unroll
      for (int i = 0; i < 12; ++i) l_logits[h*LROW + i*64 + lane] = v[i] * inv;
    }
  }
  __syncthreads();

  // phase 3: attn @ v_scalar (192 outs) and attn @ v_point (288 outs, to LDS)
  auto do_out = [&](int o) {
    int h; const float* vrow;
    if (o < 192) { h = o >> 4; vrow = vsT + (size_t)o * 768; }
    else { const int o2 = o - 192; h = o2 / 24; vrow = vpT + (size_t)o2 * 768; }
    const float4* v4 = (const float4*)vrow;
    const float4* a4 = (const float4*)(l_logits + h * LROW);
    float acc = 0.f;
    #pragma unroll 8
    for (int mq = 0; mq < 192; ++mq) {
      const float4 a = a4[mq]; const float4 x = v4[mq];
      acc = fmaf(a.x, x.x, acc); acc = fmaf(a.y, x.y, acc);
      acc = fmaf(a.z, x.z, acc); acc = fmaf(a.w, x.w, acc);
    }
    if (o < 192) fact[(size_t)n*2112 + o] = acc;
    else l_ptg[o - 192] = acc;
  };
  do_out(t);
  if (t < 224) do_out(256 + t);
  __syncthreads();

  // finish points: inverse-rotate, norm, write segments [192,576)
  if (t < 96) {
    const float* T = trans + n*3; const float* R = rot + n*9;
    const float g0 = l_ptg[t*3+0] - T[0];
    const float g1 = l_ptg[t*3+1] - T[1];
    const float g2 = l_ptg[t*3+2] - T[2];
    const float l0 = R[0]*g0 + R[3]*g1 + R[6]*g2;
    const float l1 = R[1]*g0 + R[4]*g1 + R[7]*g2;
    const float l2 = R[2]*g0 + R[5]*g1 + R[8]*g2;
    float* fo = fact + (size_t)n*2112;
    fo[192 + t] = l0;
    fo[288 + t] = l1;
    fo[384 + t] = l2;
    fo[480 + t] = sqrtf(1e-8f + l0*l0 + l1*l1 + l2*l2);
  }

  // phase 4: res_2d = attn @ in2d[n] -> segment [576,2112)
  {
    const int c = t & 127, hg = t >> 7;   // hg in {0,1}: heads hg*6..hg*6+5
    float acc[6];
    #pragma unroll
    for (int i = 0; i < 6; ++i) acc[i] = 0.f;
    const float* b2 = in2d + (size_t)n * 768 * 128 + c;
    #pragma unroll 2
    for (int m4 = 0; m4 < 192; ++m4) {
      const float v0 = b2[(size_t)(m4*4+0)*128];
      const float v1 = b2[(size_t)(m4*4+1)*128];
      const float v2 = b2[(size_t)(m4*4+2)*128];
      const float v3 = b2[(size_t)(m4*4+3)*128];
      #pragma unroll
      for (int hh = 0; hh < 6; ++hh) {
        const float4 a = ((const float4*)(l_logits + (hg*6+hh)*LROW))[m4];
        acc[hh] = fmaf(a.x, v0, acc[hh]);
        acc[hh] = fmaf(a.y, v1, acc[hh]);
        acc[hh] = fmaf(a.z, v2, acc[hh]);
        acc[hh] = fmaf(a.w, v3, acc[hh]);
      }
    }
    float* fo = fact + (size_t)n*2112 + 576 + (size_t)(hg*6)*128 + c;
    #pragma unroll
    for (int hh = 0; hh < 6; ++hh) fo[hh*128] = acc[hh];
  }
}

// ---------------- kernel 4: final projection (768x2112)@(2112x384)+b --------
__global__ __launch_bounds__(256) void k_out(
    const float* __restrict__ fact,
    const float* __restrict__ out_w, const float* __restrict__ out_b,
    float* __restrict__ out)
{
  const int t = threadIdx.x;
  const int col = blockIdx.x * 64 + (t & 63);
  const int g = __builtin_amdgcn_readfirstlane(t >> 6);
  const int n0 = blockIdx.y * 16 + g * 4;
  const float b = out_b[col];
  float acc0 = b, acc1 = b, acc2 = b, acc3 = b;
  const float* fr = fact + (size_t)n0 * 2112;   // wave-uniform -> s_load
  #pragma unroll 4
  for (int k = 0; k < 2112; ++k) {
    const float w = out_w[(size_t)k * 384 + col];
    acc0 = fmaf(fr[k],        w, acc0);
    acc1 = fmaf(fr[2112 + k], w, acc1);
    acc2 = fmaf(fr[4224 + k], w, acc2);
    acc3 = fmaf(fr[6336 + k], w, acc3);
  }
  out[(size_t)(n0+0)*384 + col] = acc0;
  out[(size_t)(n0+1)*384 + col] = acc1;
  out[(size_t)(n0+2)*384 + col] = acc2;
  out[(size_t)(n0+3)*384 + col] = acc3;
}

extern "C" void kernel_launch(void* const* d_in, const int* in_sizes, int n_in,
                              void* d_out, int out_size, void* d_ws, size_t ws_size,
                              hipStream_t stream) {
  const float* inputs_1d = (const float*)d_in[0];
  const float* inputs_2d = (const float*)d_in[1];
  const float* mask      = (const float*)d_in[2];
  const float* rot       = (const float*)d_in[3];
  const float* trans     = (const float*)d_in[4];
  const float* qs_w      = (const float*)d_in[5];
  const float* qs_b      = (const float*)d_in[6];
  const float* kvs_w     = (const float*)d_in[7];
  const float* kvs_b     = (const float*)d_in[8];
  const float* qp_w      = (const float*)d_in[9];
  const float* qp_b      = (const float*)d_in[10];
  const float* kvp_w     = (const float*)d_in[11];
  const float* kvp_b     = (const float*)d_in[12];
  const float* tpw       = (const float*)d_in[13];
  const float* a2_w      = (const float*)d_in[14];
  const float* a2_b      = (const float*)d_in[15];
  const float* out_w     = (const float*)d_in[16];
  const float* out_b     = (const float*)d_in[17];

  float* ws   = (float*)d_ws;
  float* proj = ws;                 //  768*1152 = 884736
  float* qpt  = ws + 884736;        //  768*192  = 147456
  float* kpt  = ws + 1032192;       //  768*192  = 147456
  float* vsT  = ws + 1179648;       //  192*768  = 147456
  float* vpT  = ws + 1327104;       //  288*768  = 221184
  float* fact = ws + 1548288;       //  768*2112 = 1622016  (total ~12.7 MB)
  float* out  = (float*)d_out;

  k_proj<<<dim3(18, 48), 256, 0, stream>>>(inputs_1d, qs_w, qs_b, kvs_w, kvs_b,
                                           qp_w, qp_b, kvp_w, kvp_b, proj);
  k_points<<<768, 192, 0, stream>>>(proj, rot, trans, qpt, kpt, vsT, vpT);
  k_attn<<<768, 256, 0, stream>>>(proj, inputs_2d, mask, rot, trans, tpw,
                                  a2_w, a2_b, qpt, kpt, vsT, vpT, fact);
  k_out<<<dim3(6, 48), 256, 0, stream>>>(fact, out_w, out_b, out);
}